// Round 17
// baseline (712.043 us; speedup 1.0000x reference)
//
#include <hip/hip_runtime.h>
#include <hip/hip_bf16.h>
#include <math.h>

// ---------------- constants ----------------
#define B_   8
#define N_   3136
#define C_   768
#define H_   12
#define HD_  64
#define NP_  1046          // pooled seq len: floor((3136+2-3)/3)+1
#define NPP_ 1056          // padded to multiple of 32
#define M_   (B_*N_)       // 25088 rows = 196*128
#define MKV_ (B_*NPP_)     // 8448 = 66*128

typedef __bf16 bf16x8 __attribute__((ext_vector_type(8)));
typedef float  f32x4  __attribute__((ext_vector_type(4)));

__device__ __forceinline__ float bf2f(__hip_bfloat16 v){ return __bfloat162float(v); }
__device__ __forceinline__ __hip_bfloat16 f2bf(float v){ return __float2bfloat16(v); }

__device__ __forceinline__ float fexp2(float x){ float r; asm("v_exp_f32 %0, %1" : "=v"(r) : "v"(x)); return r; }

__device__ __forceinline__ void load_lds16(const void* g, void* l) {
  __builtin_amdgcn_global_load_lds(
      (const __attribute__((address_space(1))) unsigned int*)g,
      (__attribute__((address_space(3))) unsigned int*)l, 16, 0, 0);
}

#define MFMA16(a,b,c) __builtin_amdgcn_mfma_f32_16x16x32_bf16((a),(b),(c),0,0,0)

// fast GELU: tanh form via one exp. |gelu_tanh - gelu_erf| <= ~1e-3.
__device__ __forceinline__ float gelu_f(float v) {
  float y = 1.5957691f * (v + 0.044715f * v * v * v);   // 2*sqrt(2/pi)*(...)
  float e = __expf(y);                                   // e^{2u}
  return v * e / (e + 1.0f);                             // v * 0.5*(1+tanh(u))
}

// ---------------- f32 -> bf16 convert, float4-vectorized (all 4 weight mats, one launch) ----------------
__device__ __forceinline__ void cvt4(const float* __restrict__ s, __hip_bfloat16* __restrict__ d, int i4) {
  float4 v = *(const float4*)(s + i4);
  __hip_bfloat16 o[4] = { f2bf(v.x), f2bf(v.y), f2bf(v.z), f2bf(v.w) };
  *(short4*)(d + i4) = *(const short4*)o;
}
__global__ void cvt_kernel(const float* __restrict__ s0, __hip_bfloat16* __restrict__ d0, int q0,
                           const float* __restrict__ s1, __hip_bfloat16* __restrict__ d1, int q1,
                           const float* __restrict__ s2, __hip_bfloat16* __restrict__ d2, int q2,
                           const float* __restrict__ s3, __hip_bfloat16* __restrict__ d3, int q3) {
  int i = blockIdx.x * 256 + threadIdx.x;      // quad index
  if (i < q0) { cvt4(s0, d0, i * 4); return; }
  i -= q0;
  if (i < q1) { cvt4(s1, d1, i * 4); return; }
  i -= q1;
  if (i < q2) { cvt4(s2, d2, i * 4); return; }
  i -= q2;
  if (i < q3) { cvt4(s3, d3, i * 4); }
}

// ---------------- LayerNorm (f32 in -> bf16 out), one block per row of 768 ----------------
__global__ __launch_bounds__(256)
void ln_kernel(const float* __restrict__ x, const float* __restrict__ g,
               const float* __restrict__ bta, __hip_bfloat16* __restrict__ out) {
  const size_t row = blockIdx.x;
  const float* xr = x + row * C_;
  const int t = threadIdx.x;
  float v0 = xr[t], v1 = xr[t + 256], v2 = xr[t + 512];
  float s  = v0 + v1 + v2;
  float s2 = v0*v0 + v1*v1 + v2*v2;
  #pragma unroll
  for (int off = 32; off > 0; off >>= 1) { s += __shfl_down(s, off); s2 += __shfl_down(s2, off); }
  __shared__ float ws1[4], ws2[4];
  if ((t & 63) == 0) { ws1[t >> 6] = s; ws2[t >> 6] = s2; }
  __syncthreads();
  float S  = ws1[0] + ws1[1] + ws1[2] + ws1[3];
  float S2 = ws2[0] + ws2[1] + ws2[2] + ws2[3];
  float mean = S * (1.0f / C_);
  float var  = S2 * (1.0f / C_) - mean * mean;
  float rstd = rsqrtf(var + 1e-5f);
  __hip_bfloat16* orow = out + row * C_;
  orow[t]       = f2bf((v0 - mean) * rstd * g[t]       + bta[t]);
  orow[t + 256] = f2bf((v1 - mean) * rstd * g[t + 256] + bta[t + 256]);
  orow[t + 512] = f2bf((v2 - mean) * rstd * g[t + 512] + bta[t + 512]);
}

// ---------------- pool h BEFORE the K/V projection (pooling commutes with matmul) ----------------
__global__ void pool_h_kernel(const __hip_bfloat16* __restrict__ h, __hip_bfloat16* __restrict__ hp) {
  int idx = blockIdx.x * 256 + threadIdx.x;    // total 8*1056*768
  int c  = idx % C_;
  int np = (idx / C_) % NPP_;
  int b  = idx / (C_ * NPP_);
  float a = 0.f;
  if (np < NP_) {
    #pragma unroll
    for (int t = 0; t < 3; ++t) {
      int n = np * 3 - 1 + t;
      if (n >= 0 && n < N_) a += bf2f(h[((size_t)b * N_ + n) * C_ + c]);
    }
    a *= (1.0f / 3.0f);
  }
  hp[idx] = f2bf(a);
}

// ---------------- rearrange KV gemm output -> kpb (permuted rows) + vptb (transposed) ----------------
__global__ __launch_bounds__(256)
void rearr_kernel(const __hip_bfloat16* __restrict__ kv,
                  __hip_bfloat16* __restrict__ kp, __hip_bfloat16* __restrict__ vpt) {
  __shared__ __align__(16) __hip_bfloat16 sk[32][64], sv[32][64];
  const int bh = blockIdx.y;
  const int b = bh / H_, h = bh % H_;
  const int np0 = blockIdx.x * 32;
  const int t = threadIdx.x;
  const int nl = t >> 3, d8 = (t & 7) * 8;
  const __hip_bfloat16* src = kv + ((size_t)(b * NPP_) + np0 + nl) * 1536 + h * 64;
  *(bf16x8*)&sk[nl][d8] = *(const bf16x8*)(src + d8);
  *(bf16x8*)&sv[nl][d8] = *(const bf16x8*)(src + 768 + d8);
  __syncthreads();
  {
    int lhi = nl >> 3, rr = nl & 7;
    int p = (rr < 4) ? (lhi * 4 + rr) : (16 + lhi * 4 + rr - 4);
    *(bf16x8*)(kp + ((size_t)bh * NPP_ + np0 + p) * 64 + d8) = *(const bf16x8*)&sk[nl][d8];
  }
  {
    int d = t >> 2, n8 = (t & 3) * 8;
    bf16x8 v;
    #pragma unroll
    for (int j = 0; j < 8; ++j) v[j] = sv[n8 + j][d];
    *(bf16x8*)(vpt + ((size_t)bh * 64 + d) * NPP_ + np0 + n8) = v;
  }
}

// ---------------- attention: LDS-staged K/V shared by 4 waves, 128 q-rows/block ----------------
// exp2-folded softmax; mask-free main loop + single masked tail chunk.
__global__ __launch_bounds__(256)
void attn_kernel(const __hip_bfloat16* __restrict__ qb,
                 const __hip_bfloat16* __restrict__ kp,
                 const __hip_bfloat16* __restrict__ vpt,
                 __hip_bfloat16* __restrict__ o) {
  __shared__ __align__(16) char smem[16384];   // [2 bufs][K 4KB | V 4KB]
  const int tid  = threadIdx.x;
  const int lane = tid & 63;
  const int w    = tid >> 6;
  const int bh = blockIdx.y;
  const int b = bh / H_, h = bh % H_;
  const int q0 = blockIdx.x * 128 + w * 32;
  const int l15 = lane & 15, lhi = lane >> 4;

  bf16x8 qf[2][2];
  #pragma unroll
  for (int f = 0; f < 2; ++f) {
    int qrow = q0 + f * 16 + l15;
    if (qrow >= N_) qrow = N_ - 1;
    const __hip_bfloat16* qptr = qb + ((size_t)(b * N_ + qrow)) * C_ + h * HD_ + lhi * 8;
    qf[f][0] = *(const bf16x8*)(qptr);
    qf[f][1] = *(const bf16x8*)(qptr + 32);
    #pragma unroll
    for (int i = 0; i < 8; ++i) {   // fold hd^-0.5 * log2(e) = 0.1803369 (softmax via 2^x)
      qf[f][0][i] = qf[f][0][i] * (__bf16)0.18033688f;
      qf[f][1][i] = qf[f][1][i] * (__bf16)0.18033688f;
    }
  }

  const char* kp_base  = (const char*)(kp  + (size_t)bh * NPP_ * HD_);
  const char* vpt_base = (const char*)(vpt + (size_t)bh * HD_ * NPP_);
  const int krow_s = tid >> 3;                 // 0..31
  const int pK = (tid & 7) * 16;
  const int srcKoff = krow_s * 128 + (pK ^ ((krow_s & 7) << 4));
  const int qV = pK ^ ((krow_s & 7) << 4);
  const int vrow_s = 2 * krow_s + (qV >> 6);
  const int srcVoff = vrow_s * (NPP_ * 2) + (qV & 63);

  char* dstK[2] = { smem + 0    + w * 1024, smem + 8192 + 0    + w * 1024 };
  char* dstV[2] = { smem + 4096 + w * 1024, smem + 8192 + 4096 + w * 1024 };

  load_lds16(kp_base + srcKoff, dstK[0]);
  load_lds16(vpt_base + srcVoff, dstV[0]);
  __syncthreads();

  f32x4 oacc[2][4] = {};
  float lp[2] = {0.f, 0.f};

#define ABODY(kcj, cur, MASKED) { \
    const char* sK = smem + (cur) * 8192; \
    const char* sV = smem + (cur) * 8192 + 4096; \
    bf16x8 ka0 = *(const bf16x8*)(sK + l15 * 128        + (( 0 + 16 * lhi) ^ ((l15 & 7) << 4))); \
    bf16x8 ka1 = *(const bf16x8*)(sK + l15 * 128        + ((64 + 16 * lhi) ^ ((l15 & 7) << 4))); \
    bf16x8 kb0 = *(const bf16x8*)(sK + (16 + l15) * 128 + (( 0 + 16 * lhi) ^ ((l15 & 7) << 4))); \
    bf16x8 kb1 = *(const bf16x8*)(sK + (16 + l15) * 128 + ((64 + 16 * lhi) ^ ((l15 & 7) << 4))); \
    bf16x8 vf[4]; \
    _Pragma("unroll") for (int nb = 0; nb < 4; ++nb) { \
      int row = nb * 16 + l15; \
      int Lv = row >> 1; \
      int p = (((row & 1) * 64) + 16 * lhi) ^ ((Lv & 7) << 4); \
      vf[nb] = *(const bf16x8*)(sV + Lv * 128 + p); \
    } \
    _Pragma("unroll") for (int f = 0; f < 2; ++f) { \
      f32x4 s0 = {}, s1 = {}; \
      s0 = MFMA16(ka0, qf[f][0], s0); \
      s0 = MFMA16(ka1, qf[f][1], s0); \
      s1 = MFMA16(kb0, qf[f][0], s1); \
      s1 = MFMA16(kb1, qf[f][1], s1); \
      bf16x8 pa; \
      _Pragma("unroll") for (int r = 0; r < 4; ++r) { \
        float p0 = fexp2(s0[r]); \
        float p1 = fexp2(s1[r]); \
        if (MASKED) { \
          if ((kcj) + lhi * 8 + r     >= NP_) p0 = 0.f; \
          if ((kcj) + lhi * 8 + 4 + r >= NP_) p1 = 0.f; \
        } \
        lp[f] += p0 + p1; \
        pa[r]     = (__bf16)p0; \
        pa[r + 4] = (__bf16)p1; \
      } \
      _Pragma("unroll") for (int nb = 0; nb < 4; ++nb) \
        oacc[f][nb] = MFMA16(pa, vf[nb], oacc[f][nb]); \
    } }

  for (int kc = 0; kc < 1024; kc += 32) {
    const int cur = (kc >> 5) & 1;
    load_lds16(kp_base + (size_t)(kc + 32) * 128 + srcKoff, dstK[cur ^ 1]);
    load_lds16(vpt_base + (size_t)(kc + 32) * 2 + srcVoff, dstV[cur ^ 1]);
    ABODY(kc, cur, 0);
    __syncthreads();
  }
  ABODY(1024, 0, 1);
#undef ABODY

  #pragma unroll
  for (int f = 0; f < 2; ++f) {
    float lpf = lp[f];
    lpf += __shfl_xor(lpf, 16);
    lpf += __shfl_xor(lpf, 32);
    #pragma unroll
    for (int r = 0; r < 4; ++r) {
      int orow = q0 + f * 16 + lhi * 4 + r;
      if (orow < N_) {
        float inv = 1.0f / __shfl(lpf, lhi * 4 + r);
        size_t rowbase = ((size_t)(b * N_ + orow)) * C_ + h * HD_;
        #pragma unroll
        for (int nb = 0; nb < 4; ++nb)
          o[rowbase + nb * 16 + l15] = f2bf(oacc[f][nb][r] * inv);
      }
    }
  }
}

// ---------------- 128x128 deep-pipelined GEMM (BK=32, 4 bufs, counted vmcnt) — f32+bias+res out ----------------
__global__ __launch_bounds__(256, 2)
void gemm128(const __hip_bfloat16* __restrict__ A,
             const __hip_bfloat16* __restrict__ Bt,
             const float* __restrict__ bias,
             const float* __restrict__ res, float* __restrict__ out,
             int M, int N, int K) {
  __shared__ __align__(16) __hip_bfloat16 sA[4][128 * 32];
  __shared__ __align__(16) __hip_bfloat16 sB[4][128 * 32];
  const int tid = threadIdx.x, lane = tid & 63, wid = tid >> 6;
  const int wr = wid >> 1, wc = wid & 1;
  const int l15 = lane & 15, lhi = lane >> 4;

  const int nwg = gridDim.x;
  const int ntx = N >> 7;
  const int qq = nwg >> 3, rr8 = nwg & 7;
  const int xcd = blockIdx.x & 7, off8 = blockIdx.x >> 3;
  const int wg = (xcd < rr8 ? xcd * (qq + 1) : rr8 * (qq + 1) + (xcd - rr8) * qq) + off8;
  const long row0 = (long)(wg / ntx) * 128;
  const long col0 = (long)(wg % ntx) * 128;

  const size_t ldb = (size_t)K * 2;
  const int R = tid >> 2;
  const int scol = ((tid & 3) * 16) ^ ((R & 3) << 4);
  const char* gA = (const char*)A  + (size_t)(row0 + R) * ldb + scol;
  const char* gB = (const char*)Bt + (size_t)(col0 + R) * ldb + scol;

  const int fsw = (lhi * 16) ^ ((l15 & 3) << 4);

  f32x4 acc[4][4] = {};

#define STG(b, t) { \
    const char* ga_ = gA + (size_t)(t) * 64; \
    const char* gb_ = gB + (size_t)(t) * 64; \
    char* la_ = (char*)&sA[b][0] + wid * 1024; \
    char* lb_ = (char*)&sB[b][0] + wid * 1024; \
    load_lds16(ga_, la_); \
    load_lds16(ga_ + 64 * ldb, la_ + 4096); \
    load_lds16(gb_, lb_); \
    load_lds16(gb_ + 64 * ldb, lb_ + 4096); }

  const int NT = K >> 5;
  STG(0, 0); STG(1, 1); STG(2, 2);
  asm volatile("s_waitcnt vmcnt(8)" ::: "memory");
  __syncthreads();

  for (int t = 0; t < NT; ++t) {
    const int b = t & 3;
    bf16x8 af[4], bfv[4];
    const char* pa_ = (const char*)&sA[b][0] + (wr * 64 + l15) * 64 + fsw;
    const char* pb_ = (const char*)&sB[b][0] + (wc * 64 + l15) * 64 + fsw;
    #pragma unroll
    for (int m = 0; m < 4; ++m) af[m]  = *(const bf16x8*)(pa_ + m * 16 * 64);
    #pragma unroll
    for (int n = 0; n < 4; ++n) bfv[n] = *(const bf16x8*)(pb_ + n * 16 * 64);
    if (t + 3 < NT) {
      STG((t + 3) & 3, t + 3);
      asm volatile("s_waitcnt vmcnt(8)" ::: "memory");
    } else if (t + 2 < NT) {
      asm volatile("s_waitcnt vmcnt(4)" ::: "memory");
    } else if (t + 1 < NT) {
      asm volatile("s_waitcnt vmcnt(0)" ::: "memory");
    }
    __builtin_amdgcn_sched_barrier(0);
    __builtin_amdgcn_s_barrier();
    __builtin_amdgcn_sched_barrier(0);
    __builtin_amdgcn_s_setprio(1);
    #pragma unroll
    for (int m = 0; m < 4; ++m)
      #pragma unroll
      for (int n = 0; n < 4; ++n)
        acc[m][n] = MFMA16(af[m], bfv[n], acc[m][n]);
    __builtin_amdgcn_s_setprio(0);
  }
#undef STG

  #pragma unroll
  for (int m = 0; m < 4; ++m) {
    long rbase = row0 + wr * 64 + m * 16 + lhi * 4;
    #pragma unroll
    for (int n = 0; n < 4; ++n) {
      long col = col0 + wc * 64 + n * 16 + l15;
      #pragma unroll
      for (int r = 0; r < 4; ++r) {
        size_t idx = (size_t)(rbase + r) * N + col;
        out[idx] = acc[m][n][r] + bias[col] + res[idx];
      }
    }
  }
}

// ---------------- same K-loop, bf16 output, no bias/res (Q and KV projections) ----------------
__global__ __launch_bounds__(256, 2)
void gemm128b(const __hip_bfloat16* __restrict__ A,
              const __hip_bfloat16* __restrict__ Bt,
              __hip_bfloat16* __restrict__ out,
              int M, int N, int K) {
  __shared__ __align__(16) __hip_bfloat16 sA[4][128 * 32];
  __shared__ __align__(16) __hip_bfloat16 sB[4][128 * 32];
  const int tid = threadIdx.x, lane = tid & 63, wid = tid >> 6;
  const int wr = wid >> 1, wc = wid & 1;
  const int l15 = lane & 15, lhi = lane >> 4;

  const int nwg = gridDim.x;
  const int ntx = N >> 7;
  const int qq = nwg >> 3, rr8 = nwg & 7;
  const int xcd = blockIdx.x & 7, off8 = blockIdx.x >> 3;
  const int wg = (xcd < rr8 ? xcd * (qq + 1) : rr8 * (qq + 1) + (xcd - rr8) * qq) + off8;
  const long row0 = (long)(wg / ntx) * 128;
  const long col0 = (long)(wg % ntx) * 128;

  const size_t ldb = (size_t)K * 2;
  const int R = tid >> 2;
  const int scol = ((tid & 3) * 16) ^ ((R & 3) << 4);
  const char* gA = (const char*)A  + (size_t)(row0 + R) * ldb + scol;
  const char* gB = (const char*)Bt + (size_t)(col0 + R) * ldb + scol;

  const int fsw = (lhi * 16) ^ ((l15 & 3) << 4);

  f32x4 acc[4][4] = {};

#define STG(b, t) { \
    const char* ga_ = gA + (size_t)(t) * 64; \
    const char* gb_ = gB + (size_t)(t) * 64; \
    char* la_ = (char*)&sA[b][0] + wid * 1024; \
    char* lb_ = (char*)&sB[b][0] + wid * 1024; \
    load_lds16(ga_, la_); \
    load_lds16(ga_ + 64 * ldb, la_ + 4096); \
    load_lds16(gb_, lb_); \
    load_lds16(gb_ + 64 * ldb, lb_ + 4096); }

  const int NT = K >> 5;
  STG(0, 0); STG(1, 1); STG(2, 2);
  asm volatile("s_waitcnt vmcnt(8)" ::: "memory");
  __syncthreads();

  for (int t = 0; t < NT; ++t) {
    const int b = t & 3;
    bf16x8 af[4], bfv[4];
    const char* pa_ = (const char*)&sA[b][0] + (wr * 64 + l15) * 64 + fsw;
    const char* pb_ = (const char*)&sB[b][0] + (wc * 64 + l15) * 64 + fsw;
    #pragma unroll
    for (int m = 0; m < 4; ++m) af[m]  = *(const bf16x8*)(pa_ + m * 16 * 64);
    #pragma unroll
    for (int n = 0; n < 4; ++n) bfv[n] = *(const bf16x8*)(pb_ + n * 16 * 64);
    if (t + 3 < NT) {
      STG((t + 3) & 3, t + 3);
      asm volatile("s_waitcnt vmcnt(8)" ::: "memory");
    } else if (t + 2 < NT) {
      asm volatile("s_waitcnt vmcnt(4)" ::: "memory");
    } else if (t + 1 < NT) {
      asm volatile("s_waitcnt vmcnt(0)" ::: "memory");
    }
    __builtin_amdgcn_sched_barrier(0);
    __builtin_amdgcn_s_barrier();
    __builtin_amdgcn_sched_barrier(0);
    __builtin_amdgcn_s_setprio(1);
    #pragma unroll
    for (int m = 0; m < 4; ++m)
      #pragma unroll
      for (int n = 0; n < 4; ++n)
        acc[m][n] = MFMA16(af[m], bfv[n], acc[m][n]);
    __builtin_amdgcn_s_setprio(0);
  }
#undef STG

  #pragma unroll
  for (int m = 0; m < 4; ++m) {
    long rbase = row0 + wr * 64 + m * 16 + lhi * 4;
    #pragma unroll
    for (int n = 0; n < 4; ++n) {
      long col = col0 + wc * 64 + n * 16 + l15;
      #pragma unroll
      for (int r = 0; r < 4; ++r) {
        size_t idx = (size_t)(rbase + r) * N + col;
        out[idx] = f2bf(acc[m][n][r]);
      }
    }
  }
}

// ---------------- same K-loop, gelu(acc+bias) bf16 out (fc1) — column-stripe grid decode ----------------
// NCG=12 column-stripe: each stripe's B-slab = 12*128*768*2 = 2.36 MB < 4 MB per-XCD L2,
// so wfc1 stays L2-hot within a stripe (r16 profile: FETCH 328 MB = B re-streamed per
// 128-row panel since 4.7 MB > L2). Cost: A read once per stripe (2x total = 77 MB).
__global__ __launch_bounds__(256, 2)
void gemm128g(const __hip_bfloat16* __restrict__ A,
              const __hip_bfloat16* __restrict__ Bt,
              const float* __restrict__ bias,
              __hip_bfloat16* __restrict__ out,
              int M, int N, int K) {
  __shared__ __align__(16) __hip_bfloat16 sA[4][128 * 32];
  __shared__ __align__(16) __hip_bfloat16 sB[4][128 * 32];
  const int tid = threadIdx.x, lane = tid & 63, wid = tid >> 6;
  const int wr = wid >> 1, wc = wid & 1;
  const int l15 = lane & 15, lhi = lane >> 4;

  const int nwg = gridDim.x;
  const int qq = nwg >> 3, rr8 = nwg & 7;
  const int xcd = blockIdx.x & 7, off8 = blockIdx.x >> 3;
  const int wg = (xcd < rr8 ? xcd * (qq + 1) : rr8 * (qq + 1) + (xcd - rr8) * qq) + off8;
  // column-stripe decode: stripes of NCG=12 col-tiles; rows iterate within a stripe
  const int NCG = 12;
  const int cpg = (M >> 7) * NCG;          // blocks per stripe
  const int st = wg / cpg, rem = wg % cpg;
  const long row0 = (long)(rem / NCG) * 128;
  const long col0 = (long)(st * NCG + rem % NCG) * 128;

  const size_t ldb = (size_t)K * 2;
  const int R = tid >> 2;
  const int scol = ((tid & 3) * 16) ^ ((R & 3) << 4);
  const char* gA = (const char*)A  + (size_t)(row0 + R) * ldb + scol;
  const char* gB = (const char*)Bt + (size_t)(col0 + R) * ldb + scol;

  const int fsw = (lhi * 16) ^ ((l15 & 3) << 4);

  f32x4 acc[4][4] = {};

#define STG(b, t) { \
    const char* ga_ = gA + (size_t)(t) * 64; \
    const char* gb_ = gB + (size_t)(t) * 64; \
    char* la_ = (char*)&sA[b][0] + wid * 1024; \
    char* lb_ = (char*)&sB[b][0] + wid * 1024; \
    load_lds16(ga_, la_); \
    load_lds16(ga_ + 64 * ldb, la_ + 4096); \
    load_lds16(gb_, lb_); \
    load_lds16(gb_ + 64 * ldb, lb_ + 4096); }

  const int NT = K >> 5;
  STG(0, 0); STG(1, 1); STG(2, 2);
  asm volatile("s_waitcnt vmcnt(8)" ::: "memory");
  __syncthreads();

  for (int t = 0; t < NT; ++t) {
    const int b = t & 3;
    bf16x8 af[4], bfv[4];
    const char* pa_ = (const char*)&sA[b][0] + (wr * 64 + l15) * 64 + fsw;
    const char* pb_ = (const char*)&sB[b][0] + (wc * 64 + l15) * 64 + fsw;
    #pragma unroll
    for (int m = 0; m < 4; ++m) af[m]  = *(const bf16x8*)(pa_ + m * 16 * 64);
    #pragma unroll
    for (int n = 0; n < 4; ++n) bfv[n] = *(const bf16x8*)(pb_ + n * 16 * 64);
    if (t + 3 < NT) {
      STG((t + 3) & 3, t + 3);
      asm volatile("s_waitcnt vmcnt(8)" ::: "memory");
    } else if (t + 2 < NT) {
      asm volatile("s_waitcnt vmcnt(4)" ::: "memory");
    } else if (t + 1 < NT) {
      asm volatile("s_waitcnt vmcnt(0)" ::: "memory");
    }
    __builtin_amdgcn_sched_barrier(0);
    __builtin_amdgcn_s_barrier();
    __builtin_amdgcn_sched_barrier(0);
    __builtin_amdgcn_s_setprio(1);
    #pragma unroll
    for (int m = 0; m < 4; ++m)
      #pragma unroll
      for (int n = 0; n < 4; ++n)
        acc[m][n] = MFMA16(af[m], bfv[n], acc[m][n]);
    __builtin_amdgcn_s_setprio(0);
  }
#undef STG

  #pragma unroll
  for (int m = 0; m < 4; ++m) {
    long rbase = row0 + wr * 64 + m * 16 + lhi * 4;
    #pragma unroll
    for (int n = 0; n < 4; ++n) {
      long col = col0 + wc * 64 + n * 16 + l15;
      #pragma unroll
      for (int r = 0; r < 4; ++r) {
        size_t idx = (size_t)(rbase + r) * N + col;
        out[idx] = f2bf(gelu_f(acc[m][n][r] + bias[col]));
      }
    }
  }
}

// ---------------- launch ----------------
extern "C" void kernel_launch(void* const* d_in, const int* in_sizes, int n_in,
                              void* d_out, int out_size, void* d_ws, size_t ws_size,
                              hipStream_t stream) {
  const float* x      = (const float*)d_in[0];
  const float* ln1_g  = (const float*)d_in[1];
  const float* ln1_b  = (const float*)d_in[2];
  const float* qkv_w  = (const float*)d_in[3];
  const float* proj_w = (const float*)d_in[4];
  const float* proj_b = (const float*)d_in[5];
  const float* ln2_g  = (const float*)d_in[6];
  const float* ln2_b  = (const float*)d_in[7];
  const float* fc1_w  = (const float*)d_in[8];
  const float* fc1_b  = (const float*)d_in[9];
  const float* fc2_w  = (const float*)d_in[10];
  const float* fc2_b  = (const float*)d_in[11];
  float* out = (float*)d_out;

  // workspace layout (bytes)
  char* ws = (char*)d_ws;
  __hip_bfloat16* wqkv  = (__hip_bfloat16*)(ws + 0);          // 2304*768*2  = 3538944
  __hip_bfloat16* wproj = (__hip_bfloat16*)(ws + 3538944);    // 768*768*2   = 1179648
  __hip_bfloat16* wfc1  = (__hip_bfloat16*)(ws + 4718592);    // 3072*768*2  = 4718592
  __hip_bfloat16* wfc2  = (__hip_bfloat16*)(ws + 9437184);    // 768*3072*2  = 4718592
  __hip_bfloat16* hbuf  = (__hip_bfloat16*)(ws + 14155776);   // 25088*768*2 = 38535168 (LN1/LN2 out)
  __hip_bfloat16* obuf  = (__hip_bfloat16*)(ws + 52690944);   // 25088*768*2 = 38535168 (attn out)
  __hip_bfloat16* kpb   = (__hip_bfloat16*)(ws + 91226112);   // 96*1056*64*2 = 12976128
  __hip_bfloat16* vptb  = (__hip_bfloat16*)(ws + 104202240);  // 12976128
  __hip_bfloat16* big   = (__hip_bfloat16*)(ws + 117178368);  // 154140672 (fc1 m1; earlier Q|KV|hp)
  const size_t WS_NEEDED = 117178368ull + 154140672ull;       // ~271.3 MB
  if (ws_size < WS_NEEDED) return;

  // sub-buffers carved from big (all consumed before fc1 overwrites big)
  __hip_bfloat16* qb   = big;                                        // 25088*768*2 = 38535168
  __hip_bfloat16* kvb  = (__hip_bfloat16*)((char*)big + 38535168);   // 8448*1536*2 = 25952256
  __hip_bfloat16* hp   = (__hip_bfloat16*)((char*)big + 64487424);   // 8448*768*2  = 12976128

  // weights -> bf16 (single vectorized launch)
  {
    int q0 = (2304 * 768) / 4, q1 = (768 * 768) / 4, q2 = (3072 * 768) / 4, q3 = (768 * 3072) / 4;
    int tot = q0 + q1 + q2 + q3;
    cvt_kernel<<<(tot + 255) / 256, 256, 0, stream>>>(qkv_w, wqkv, q0, proj_w, wproj, q1,
                                                      fc1_w, wfc1, q2, fc2_w, wfc2, q3);
  }

  // attention sublayer: pool-then-project for K/V (exact: pooling commutes with matmul)
  ln_kernel<<<M_, 256, 0, stream>>>(x, ln1_g, ln1_b, hbuf);
  gemm128b<<<(M_ / 128) * (768 / 128), 256, 0, stream>>>(hbuf, wqkv, qb, M_, 768, 768);
  pool_h_kernel<<<(B_ * NPP_ * C_) / 256, 256, 0, stream>>>(hbuf, hp);
  gemm128b<<<(MKV_ / 128) * (1536 / 128), 256, 0, stream>>>(hp, wqkv + 768 * 768, kvb, MKV_, 1536, 768);
  rearr_kernel<<<dim3(NPP_ / 32, B_ * H_), 256, 0, stream>>>(kvb, kpb, vptb);
  attn_kernel<<<dim3((N_ + 127) / 128, B_ * H_), 256, 0, stream>>>(qb, kpb, vptb, obuf);
  gemm128<<<(M_ / 128) * (768 / 128), 256, 0, stream>>>(obuf, wproj, proj_b, x, out, M_, 768, 768);

  // MLP sublayer (x1 lives in d_out)
  ln_kernel<<<M_, 256, 0, stream>>>(out, ln2_g, ln2_b, hbuf);
  gemm128g<<<(M_ / 128) * (3072 / 128), 256, 0, stream>>>(hbuf, wfc1, fc1_b, big, M_, 3072, 768);
  gemm128<<<(M_ / 128) * (768 / 128), 256, 0, stream>>>(big, wfc2, fc2_b, out, out, M_, 768, 3072);
}

// Round 18
// 683.592 us; speedup vs baseline: 1.0416x; 1.0416x over previous
//
#include <hip/hip_runtime.h>
#include <hip/hip_bf16.h>
#include <math.h>

// ---------------- constants ----------------
#define B_   8
#define N_   3136
#define C_   768
#define H_   12
#define HD_  64
#define NP_  1046          // pooled seq len: floor((3136+2-3)/3)+1
#define NPP_ 1056          // padded to multiple of 32
#define M_   (B_*N_)       // 25088 rows = 196*128
#define MKV_ (B_*NPP_)     // 8448 = 66*128

typedef __bf16 bf16x8 __attribute__((ext_vector_type(8)));
typedef float  f32x4  __attribute__((ext_vector_type(4)));

__device__ __forceinline__ float bf2f(__hip_bfloat16 v){ return __bfloat162float(v); }
__device__ __forceinline__ __hip_bfloat16 f2bf(float v){ return __float2bfloat16(v); }

__device__ __forceinline__ void load_lds16(const void* g, void* l) {
  __builtin_amdgcn_global_load_lds(
      (const __attribute__((address_space(1))) unsigned int*)g,
      (__attribute__((address_space(3))) unsigned int*)l, 16, 0, 0);
}

#define MFMA16(a,b,c) __builtin_amdgcn_mfma_f32_16x16x32_bf16((a),(b),(c),0,0,0)

// fast GELU: tanh form via one exp. |gelu_tanh - gelu_erf| <= ~1e-3.
__device__ __forceinline__ float gelu_f(float v) {
  float y = 1.5957691f * (v + 0.044715f * v * v * v);   // 2*sqrt(2/pi)*(...)
  float e = __expf(y);                                   // e^{2u}
  return v * e / (e + 1.0f);                             // v * 0.5*(1+tanh(u))
}

// ---------------- f32 -> bf16 convert, float4-vectorized (all 4 weight mats, one launch) ----------------
__device__ __forceinline__ void cvt4(const float* __restrict__ s, __hip_bfloat16* __restrict__ d, int i4) {
  float4 v = *(const float4*)(s + i4);
  __hip_bfloat16 o[4] = { f2bf(v.x), f2bf(v.y), f2bf(v.z), f2bf(v.w) };
  *(short4*)(d + i4) = *(const short4*)o;
}
__global__ void cvt_kernel(const float* __restrict__ s0, __hip_bfloat16* __restrict__ d0, int q0,
                           const float* __restrict__ s1, __hip_bfloat16* __restrict__ d1, int q1,
                           const float* __restrict__ s2, __hip_bfloat16* __restrict__ d2, int q2,
                           const float* __restrict__ s3, __hip_bfloat16* __restrict__ d3, int q3) {
  int i = blockIdx.x * 256 + threadIdx.x;      // quad index
  if (i < q0) { cvt4(s0, d0, i * 4); return; }
  i -= q0;
  if (i < q1) { cvt4(s1, d1, i * 4); return; }
  i -= q1;
  if (i < q2) { cvt4(s2, d2, i * 4); return; }
  i -= q2;
  if (i < q3) { cvt4(s3, d3, i * 4); }
}

// ---------------- LayerNorm (f32 in -> bf16 out), one block per row of 768 ----------------
__global__ __launch_bounds__(256)
void ln_kernel(const float* __restrict__ x, const float* __restrict__ g,
               const float* __restrict__ bta, __hip_bfloat16* __restrict__ out) {
  const size_t row = blockIdx.x;
  const float* xr = x + row * C_;
  const int t = threadIdx.x;
  float v0 = xr[t], v1 = xr[t + 256], v2 = xr[t + 512];
  float s  = v0 + v1 + v2;
  float s2 = v0*v0 + v1*v1 + v2*v2;
  #pragma unroll
  for (int off = 32; off > 0; off >>= 1) { s += __shfl_down(s, off); s2 += __shfl_down(s2, off); }
  __shared__ float ws1[4], ws2[4];
  if ((t & 63) == 0) { ws1[t >> 6] = s; ws2[t >> 6] = s2; }
  __syncthreads();
  float S  = ws1[0] + ws1[1] + ws1[2] + ws1[3];
  float S2 = ws2[0] + ws2[1] + ws2[2] + ws2[3];
  float mean = S * (1.0f / C_);
  float var  = S2 * (1.0f / C_) - mean * mean;
  float rstd = rsqrtf(var + 1e-5f);
  __hip_bfloat16* orow = out + row * C_;
  orow[t]       = f2bf((v0 - mean) * rstd * g[t]       + bta[t]);
  orow[t + 256] = f2bf((v1 - mean) * rstd * g[t + 256] + bta[t + 256]);
  orow[t + 512] = f2bf((v2 - mean) * rstd * g[t + 512] + bta[t + 512]);
}

// ---------------- pool h BEFORE the K/V projection (pooling commutes with matmul) ----------------
__global__ void pool_h_kernel(const __hip_bfloat16* __restrict__ h, __hip_bfloat16* __restrict__ hp) {
  int idx = blockIdx.x * 256 + threadIdx.x;    // total 8*1056*768
  int c  = idx % C_;
  int np = (idx / C_) % NPP_;
  int b  = idx / (C_ * NPP_);
  float a = 0.f;
  if (np < NP_) {
    #pragma unroll
    for (int t = 0; t < 3; ++t) {
      int n = np * 3 - 1 + t;
      if (n >= 0 && n < N_) a += bf2f(h[((size_t)b * N_ + n) * C_ + c]);
    }
    a *= (1.0f / 3.0f);
  }
  hp[idx] = f2bf(a);
}

// ---------------- rearrange KV gemm output -> kpb (permuted rows) + vptb (transposed) ----------------
__global__ __launch_bounds__(256)
void rearr_kernel(const __hip_bfloat16* __restrict__ kv,
                  __hip_bfloat16* __restrict__ kp, __hip_bfloat16* __restrict__ vpt) {
  __shared__ __align__(16) __hip_bfloat16 sk[32][64], sv[32][64];
  const int bh = blockIdx.y;
  const int b = bh / H_, h = bh % H_;
  const int np0 = blockIdx.x * 32;
  const int t = threadIdx.x;
  const int nl = t >> 3, d8 = (t & 7) * 8;
  const __hip_bfloat16* src = kv + ((size_t)(b * NPP_) + np0 + nl) * 1536 + h * 64;
  *(bf16x8*)&sk[nl][d8] = *(const bf16x8*)(src + d8);
  *(bf16x8*)&sv[nl][d8] = *(const bf16x8*)(src + 768 + d8);
  __syncthreads();
  {
    int lhi = nl >> 3, rr = nl & 7;
    int p = (rr < 4) ? (lhi * 4 + rr) : (16 + lhi * 4 + rr - 4);
    *(bf16x8*)(kp + ((size_t)bh * NPP_ + np0 + p) * 64 + d8) = *(const bf16x8*)&sk[nl][d8];
  }
  {
    int d = t >> 2, n8 = (t & 3) * 8;
    bf16x8 v;
    #pragma unroll
    for (int j = 0; j < 8; ++j) v[j] = sv[n8 + j][d];
    *(bf16x8*)(vpt + ((size_t)bh * 64 + d) * NPP_ + np0 + n8) = v;
  }
}

// ---------------- attention: LDS-staged K/V shared by 4 waves, 128 q-rows/block ----------------
__global__ __launch_bounds__(256)
void attn_kernel(const __hip_bfloat16* __restrict__ qb,
                 const __hip_bfloat16* __restrict__ kp,
                 const __hip_bfloat16* __restrict__ vpt,
                 __hip_bfloat16* __restrict__ o) {
  __shared__ __align__(16) char smem[16384];   // [2 bufs][K 4KB | V 4KB]
  const int tid  = threadIdx.x;
  const int lane = tid & 63;
  const int w    = tid >> 6;
  const int bh = blockIdx.y;
  const int b = bh / H_, h = bh % H_;
  const int q0 = blockIdx.x * 128 + w * 32;
  const int l15 = lane & 15, lhi = lane >> 4;

  bf16x8 qf[2][2];
  #pragma unroll
  for (int f = 0; f < 2; ++f) {
    int qrow = q0 + f * 16 + l15;
    if (qrow >= N_) qrow = N_ - 1;
    const __hip_bfloat16* qptr = qb + ((size_t)(b * N_ + qrow)) * C_ + h * HD_ + lhi * 8;
    qf[f][0] = *(const bf16x8*)(qptr);
    qf[f][1] = *(const bf16x8*)(qptr + 32);
    #pragma unroll
    for (int i = 0; i < 8; ++i) {   // fold in hd^-0.5 = 0.125 (exact)
      qf[f][0][i] = qf[f][0][i] * (__bf16)0.125f;
      qf[f][1][i] = qf[f][1][i] * (__bf16)0.125f;
    }
  }

  const char* kp_base  = (const char*)(kp  + (size_t)bh * NPP_ * HD_);
  const char* vpt_base = (const char*)(vpt + (size_t)bh * HD_ * NPP_);
  const int krow_s = tid >> 3;                 // 0..31
  const int pK = (tid & 7) * 16;
  const int srcKoff = krow_s * 128 + (pK ^ ((krow_s & 7) << 4));
  const int qV = pK ^ ((krow_s & 7) << 4);
  const int vrow_s = 2 * krow_s + (qV >> 6);
  const int srcVoff = vrow_s * (NPP_ * 2) + (qV & 63);

  char* dstK[2] = { smem + 0    + w * 1024, smem + 8192 + 0    + w * 1024 };
  char* dstV[2] = { smem + 4096 + w * 1024, smem + 8192 + 4096 + w * 1024 };

  load_lds16(kp_base + srcKoff, dstK[0]);
  load_lds16(vpt_base + srcVoff, dstV[0]);
  __syncthreads();

  f32x4 oacc[2][4] = {};
  float lp[2] = {0.f, 0.f};

  for (int kc = 0; kc < NPP_; kc += 32) {
    const int cur = (kc >> 5) & 1;
    if (kc + 32 < NPP_) {
      load_lds16(kp_base + (size_t)(kc + 32) * 128 + srcKoff, dstK[cur ^ 1]);
      load_lds16(vpt_base + (size_t)(kc + 32) * 2 + srcVoff, dstV[cur ^ 1]);
    }
    const char* sK = smem + cur * 8192;
    const char* sV = smem + cur * 8192 + 4096;

    bf16x8 ka0 = *(const bf16x8*)(sK + l15 * 128        + (( 0 + 16 * lhi) ^ ((l15 & 7) << 4)));
    bf16x8 ka1 = *(const bf16x8*)(sK + l15 * 128        + ((64 + 16 * lhi) ^ ((l15 & 7) << 4)));
    bf16x8 kb0 = *(const bf16x8*)(sK + (16 + l15) * 128 + (( 0 + 16 * lhi) ^ ((l15 & 7) << 4)));
    bf16x8 kb1 = *(const bf16x8*)(sK + (16 + l15) * 128 + ((64 + 16 * lhi) ^ ((l15 & 7) << 4)));
    bf16x8 vf[4];
    #pragma unroll
    for (int nb = 0; nb < 4; ++nb) {
      int row = nb * 16 + l15;
      int Lv = row >> 1;
      int p = (((row & 1) * 64) + 16 * lhi) ^ ((Lv & 7) << 4);
      vf[nb] = *(const bf16x8*)(sV + Lv * 128 + p);
    }

    #pragma unroll
    for (int f = 0; f < 2; ++f) {
      f32x4 s0 = {}, s1 = {};
      s0 = MFMA16(ka0, qf[f][0], s0);
      s0 = MFMA16(ka1, qf[f][1], s0);
      s1 = MFMA16(kb0, qf[f][0], s1);
      s1 = MFMA16(kb1, qf[f][1], s1);
      bf16x8 pa;
      #pragma unroll
      for (int r = 0; r < 4; ++r) {
        float p0 = (kc + lhi * 8 + r     < NP_) ? __expf(s0[r]) : 0.f;
        float p1 = (kc + lhi * 8 + 4 + r < NP_) ? __expf(s1[r]) : 0.f;
        lp[f] += p0 + p1;
        pa[r]     = (__bf16)p0;
        pa[r + 4] = (__bf16)p1;
      }
      #pragma unroll
      for (int nb = 0; nb < 4; ++nb)
        oacc[f][nb] = MFMA16(pa, vf[nb], oacc[f][nb]);
    }
    __syncthreads();
  }

  #pragma unroll
  for (int f = 0; f < 2; ++f) {
    float lpf = lp[f];
    lpf += __shfl_xor(lpf, 16);
    lpf += __shfl_xor(lpf, 32);
    #pragma unroll
    for (int r = 0; r < 4; ++r) {
      int orow = q0 + f * 16 + lhi * 4 + r;
      if (orow < N_) {
        float inv = 1.0f / __shfl(lpf, lhi * 4 + r);
        size_t rowbase = ((size_t)(b * N_ + orow)) * C_ + h * HD_;
        #pragma unroll
        for (int nb = 0; nb < 4; ++nb)
          o[rowbase + nb * 16 + l15] = f2bf(oacc[f][nb][r] * inv);
      }
    }
  }
}

// ---------------- 128x128 deep-pipelined GEMM (BK=32, 4 bufs, counted vmcnt) — f32+bias+res out ----------------
__global__ __launch_bounds__(256, 2)
void gemm128(const __hip_bfloat16* __restrict__ A,
             const __hip_bfloat16* __restrict__ Bt,
             const float* __restrict__ bias,
             const float* __restrict__ res, float* __restrict__ out,
             int M, int N, int K) {
  __shared__ __align__(16) __hip_bfloat16 sA[4][128 * 32];
  __shared__ __align__(16) __hip_bfloat16 sB[4][128 * 32];
  const int tid = threadIdx.x, lane = tid & 63, wid = tid >> 6;
  const int wr = wid >> 1, wc = wid & 1;
  const int l15 = lane & 15, lhi = lane >> 4;

  const int nwg = gridDim.x;
  const int ntx = N >> 7;
  const int qq = nwg >> 3, rr8 = nwg & 7;
  const int xcd = blockIdx.x & 7, off8 = blockIdx.x >> 3;
  const int wg = (xcd < rr8 ? xcd * (qq + 1) : rr8 * (qq + 1) + (xcd - rr8) * qq) + off8;
  const long row0 = (long)(wg / ntx) * 128;
  const long col0 = (long)(wg % ntx) * 128;

  const size_t ldb = (size_t)K * 2;
  const int R = tid >> 2;
  const int scol = ((tid & 3) * 16) ^ ((R & 3) << 4);
  const char* gA = (const char*)A  + (size_t)(row0 + R) * ldb + scol;
  const char* gB = (const char*)Bt + (size_t)(col0 + R) * ldb + scol;

  const int fsw = (lhi * 16) ^ ((l15 & 3) << 4);

  f32x4 acc[4][4] = {};

#define STG(b, t) { \
    const char* ga_ = gA + (size_t)(t) * 64; \
    const char* gb_ = gB + (size_t)(t) * 64; \
    char* la_ = (char*)&sA[b][0] + wid * 1024; \
    char* lb_ = (char*)&sB[b][0] + wid * 1024; \
    load_lds16(ga_, la_); \
    load_lds16(ga_ + 64 * ldb, la_ + 4096); \
    load_lds16(gb_, lb_); \
    load_lds16(gb_ + 64 * ldb, lb_ + 4096); }

  const int NT = K >> 5;
  STG(0, 0); STG(1, 1); STG(2, 2);
  asm volatile("s_waitcnt vmcnt(8)" ::: "memory");
  __syncthreads();

  for (int t = 0; t < NT; ++t) {
    const int b = t & 3;
    bf16x8 af[4], bfv[4];
    const char* pa_ = (const char*)&sA[b][0] + (wr * 64 + l15) * 64 + fsw;
    const char* pb_ = (const char*)&sB[b][0] + (wc * 64 + l15) * 64 + fsw;
    #pragma unroll
    for (int m = 0; m < 4; ++m) af[m]  = *(const bf16x8*)(pa_ + m * 16 * 64);
    #pragma unroll
    for (int n = 0; n < 4; ++n) bfv[n] = *(const bf16x8*)(pb_ + n * 16 * 64);
    if (t + 3 < NT) {
      STG((t + 3) & 3, t + 3);
      asm volatile("s_waitcnt vmcnt(8)" ::: "memory");
    } else if (t + 2 < NT) {
      asm volatile("s_waitcnt vmcnt(4)" ::: "memory");
    } else if (t + 1 < NT) {
      asm volatile("s_waitcnt vmcnt(0)" ::: "memory");
    }
    __builtin_amdgcn_sched_barrier(0);
    __builtin_amdgcn_s_barrier();
    __builtin_amdgcn_sched_barrier(0);
    __builtin_amdgcn_s_setprio(1);
    #pragma unroll
    for (int m = 0; m < 4; ++m)
      #pragma unroll
      for (int n = 0; n < 4; ++n)
        acc[m][n] = MFMA16(af[m], bfv[n], acc[m][n]);
    __builtin_amdgcn_s_setprio(0);
  }
#undef STG

  #pragma unroll
  for (int m = 0; m < 4; ++m) {
    long rbase = row0 + wr * 64 + m * 16 + lhi * 4;
    #pragma unroll
    for (int n = 0; n < 4; ++n) {
      long col = col0 + wc * 64 + n * 16 + l15;
      #pragma unroll
      for (int r = 0; r < 4; ++r) {
        size_t idx = (size_t)(rbase + r) * N + col;
        out[idx] = acc[m][n][r] + bias[col] + res[idx];
      }
    }
  }
}

// ---------------- same K-loop, bf16 output, no bias/res (Q and KV projections) ----------------
__global__ __launch_bounds__(256, 2)
void gemm128b(const __hip_bfloat16* __restrict__ A,
              const __hip_bfloat16* __restrict__ Bt,
              __hip_bfloat16* __restrict__ out,
              int M, int N, int K) {
  __shared__ __align__(16) __hip_bfloat16 sA[4][128 * 32];
  __shared__ __align__(16) __hip_bfloat16 sB[4][128 * 32];
  const int tid = threadIdx.x, lane = tid & 63, wid = tid >> 6;
  const int wr = wid >> 1, wc = wid & 1;
  const int l15 = lane & 15, lhi = lane >> 4;

  const int nwg = gridDim.x;
  const int ntx = N >> 7;
  const int qq = nwg >> 3, rr8 = nwg & 7;
  const int xcd = blockIdx.x & 7, off8 = blockIdx.x >> 3;
  const int wg = (xcd < rr8 ? xcd * (qq + 1) : rr8 * (qq + 1) + (xcd - rr8) * qq) + off8;
  const long row0 = (long)(wg / ntx) * 128;
  const long col0 = (long)(wg % ntx) * 128;

  const size_t ldb = (size_t)K * 2;
  const int R = tid >> 2;
  const int scol = ((tid & 3) * 16) ^ ((R & 3) << 4);
  const char* gA = (const char*)A  + (size_t)(row0 + R) * ldb + scol;
  const char* gB = (const char*)Bt + (size_t)(col0 + R) * ldb + scol;

  const int fsw = (lhi * 16) ^ ((l15 & 3) << 4);

  f32x4 acc[4][4] = {};

#define STG(b, t) { \
    const char* ga_ = gA + (size_t)(t) * 64; \
    const char* gb_ = gB + (size_t)(t) * 64; \
    char* la_ = (char*)&sA[b][0] + wid * 1024; \
    char* lb_ = (char*)&sB[b][0] + wid * 1024; \
    load_lds16(ga_, la_); \
    load_lds16(ga_ + 64 * ldb, la_ + 4096); \
    load_lds16(gb_, lb_); \
    load_lds16(gb_ + 64 * ldb, lb_ + 4096); }

  const int NT = K >> 5;
  STG(0, 0); STG(1, 1); STG(2, 2);
  asm volatile("s_waitcnt vmcnt(8)" ::: "memory");
  __syncthreads();

  for (int t = 0; t < NT; ++t) {
    const int b = t & 3;
    bf16x8 af[4], bfv[4];
    const char* pa_ = (const char*)&sA[b][0] + (wr * 64 + l15) * 64 + fsw;
    const char* pb_ = (const char*)&sB[b][0] + (wc * 64 + l15) * 64 + fsw;
    #pragma unroll
    for (int m = 0; m < 4; ++m) af[m]  = *(const bf16x8*)(pa_ + m * 16 * 64);
    #pragma unroll
    for (int n = 0; n < 4; ++n) bfv[n] = *(const bf16x8*)(pb_ + n * 16 * 64);
    if (t + 3 < NT) {
      STG((t + 3) & 3, t + 3);
      asm volatile("s_waitcnt vmcnt(8)" ::: "memory");
    } else if (t + 2 < NT) {
      asm volatile("s_waitcnt vmcnt(4)" ::: "memory");
    } else if (t + 1 < NT) {
      asm volatile("s_waitcnt vmcnt(0)" ::: "memory");
    }
    __builtin_amdgcn_sched_barrier(0);
    __builtin_amdgcn_s_barrier();
    __builtin_amdgcn_sched_barrier(0);
    __builtin_amdgcn_s_setprio(1);
    #pragma unroll
    for (int m = 0; m < 4; ++m)
      #pragma unroll
      for (int n = 0; n < 4; ++n)
        acc[m][n] = MFMA16(af[m], bfv[n], acc[m][n]);
    __builtin_amdgcn_s_setprio(0);
  }
#undef STG

  #pragma unroll
  for (int m = 0; m < 4; ++m) {
    long rbase = row0 + wr * 64 + m * 16 + lhi * 4;
    #pragma unroll
    for (int n = 0; n < 4; ++n) {
      long col = col0 + wc * 64 + n * 16 + l15;
      #pragma unroll
      for (int r = 0; r < 4; ++r) {
        size_t idx = (size_t)(rbase + r) * N + col;
        out[idx] = f2bf(acc[m][n][r]);
      }
    }
  }
}

// ---------------- same K-loop, gelu(acc+bias) bf16 output (fc1) — dedicated non-template copy ----------------
__global__ __launch_bounds__(256, 2)
void gemm128g(const __hip_bfloat16* __restrict__ A,
              const __hip_bfloat16* __restrict__ Bt,
              const float* __restrict__ bias,
              __hip_bfloat16* __restrict__ out,
              int M, int N, int K) {
  __shared__ __align__(16) __hip_bfloat16 sA[4][128 * 32];
  __shared__ __align__(16) __hip_bfloat16 sB[4][128 * 32];
  const int tid = threadIdx.x, lane = tid & 63, wid = tid >> 6;
  const int wr = wid >> 1, wc = wid & 1;
  const int l15 = lane & 15, lhi = lane >> 4;

  const int nwg = gridDim.x;
  const int ntx = N >> 7;
  const int qq = nwg >> 3, rr8 = nwg & 7;
  const int xcd = blockIdx.x & 7, off8 = blockIdx.x >> 3;
  const int wg = (xcd < rr8 ? xcd * (qq + 1) : rr8 * (qq + 1) + (xcd - rr8) * qq) + off8;
  const long row0 = (long)(wg / ntx) * 128;
  const long col0 = (long)(wg % ntx) * 128;

  const size_t ldb = (size_t)K * 2;
  const int R = tid >> 2;
  const int scol = ((tid & 3) * 16) ^ ((R & 3) << 4);
  const char* gA = (const char*)A  + (size_t)(row0 + R) * ldb + scol;
  const char* gB = (const char*)Bt + (size_t)(col0 + R) * ldb + scol;

  const int fsw = (lhi * 16) ^ ((l15 & 3) << 4);

  f32x4 acc[4][4] = {};

#define STG(b, t) { \
    const char* ga_ = gA + (size_t)(t) * 64; \
    const char* gb_ = gB + (size_t)(t) * 64; \
    char* la_ = (char*)&sA[b][0] + wid * 1024; \
    char* lb_ = (char*)&sB[b][0] + wid * 1024; \
    load_lds16(ga_, la_); \
    load_lds16(ga_ + 64 * ldb, la_ + 4096); \
    load_lds16(gb_, lb_); \
    load_lds16(gb_ + 64 * ldb, lb_ + 4096); }

  const int NT = K >> 5;
  STG(0, 0); STG(1, 1); STG(2, 2);
  asm volatile("s_waitcnt vmcnt(8)" ::: "memory");
  __syncthreads();

  for (int t = 0; t < NT; ++t) {
    const int b = t & 3;
    bf16x8 af[4], bfv[4];
    const char* pa_ = (const char*)&sA[b][0] + (wr * 64 + l15) * 64 + fsw;
    const char* pb_ = (const char*)&sB[b][0] + (wc * 64 + l15) * 64 + fsw;
    #pragma unroll
    for (int m = 0; m < 4; ++m) af[m]  = *(const bf16x8*)(pa_ + m * 16 * 64);
    #pragma unroll
    for (int n = 0; n < 4; ++n) bfv[n] = *(const bf16x8*)(pb_ + n * 16 * 64);
    if (t + 3 < NT) {
      STG((t + 3) & 3, t + 3);
      asm volatile("s_waitcnt vmcnt(8)" ::: "memory");
    } else if (t + 2 < NT) {
      asm volatile("s_waitcnt vmcnt(4)" ::: "memory");
    } else if (t + 1 < NT) {
      asm volatile("s_waitcnt vmcnt(0)" ::: "memory");
    }
    __builtin_amdgcn_sched_barrier(0);
    __builtin_amdgcn_s_barrier();
    __builtin_amdgcn_sched_barrier(0);
    __builtin_amdgcn_s_setprio(1);
    #pragma unroll
    for (int m = 0; m < 4; ++m)
      #pragma unroll
      for (int n = 0; n < 4; ++n)
        acc[m][n] = MFMA16(af[m], bfv[n], acc[m][n]);
    __builtin_amdgcn_s_setprio(0);
  }
#undef STG

  #pragma unroll
  for (int m = 0; m < 4; ++m) {
    long rbase = row0 + wr * 64 + m * 16 + lhi * 4;
    #pragma unroll
    for (int n = 0; n < 4; ++n) {
      long col = col0 + wc * 64 + n * 16 + l15;
      #pragma unroll
      for (int r = 0; r < 4; ++r) {
        size_t idx = (size_t)(rbase + r) * N + col;
        out[idx] = f2bf(gelu_f(acc[m][n][r] + bias[col]));
      }
    }
  }
}

// ---------------- launch ----------------
extern "C" void kernel_launch(void* const* d_in, const int* in_sizes, int n_in,
                              void* d_out, int out_size, void* d_ws, size_t ws_size,
                              hipStream_t stream) {
  const float* x      = (const float*)d_in[0];
  const float* ln1_g  = (const float*)d_in[1];
  const float* ln1_b  = (const float*)d_in[2];
  const float* qkv_w  = (const float*)d_in[3];
  const float* proj_w = (const float*)d_in[4];
  const float* proj_b = (const float*)d_in[5];
  const float* ln2_g  = (const float*)d_in[6];
  const float* ln2_b  = (const float*)d_in[7];
  const float* fc1_w  = (const float*)d_in[8];
  const float* fc1_b  = (const float*)d_in[9];
  const float* fc2_w  = (const float*)d_in[10];
  const float* fc2_b  = (const float*)d_in[11];
  float* out = (float*)d_out;

  // workspace layout (bytes)
  char* ws = (char*)d_ws;
  __hip_bfloat16* wqkv  = (__hip_bfloat16*)(ws + 0);          // 2304*768*2  = 3538944
  __hip_bfloat16* wproj = (__hip_bfloat16*)(ws + 3538944);    // 768*768*2   = 1179648
  __hip_bfloat16* wfc1  = (__hip_bfloat16*)(ws + 4718592);    // 3072*768*2  = 4718592
  __hip_bfloat16* wfc2  = (__hip_bfloat16*)(ws + 9437184);    // 768*3072*2  = 4718592
  __hip_bfloat16* hbuf  = (__hip_bfloat16*)(ws + 14155776);   // 25088*768*2 = 38535168 (LN1/LN2 out)
  __hip_bfloat16* obuf  = (__hip_bfloat16*)(ws + 52690944);   // 25088*768*2 = 38535168 (attn out)
  __hip_bfloat16* kpb   = (__hip_bfloat16*)(ws + 91226112);   // 96*1056*64*2 = 12976128
  __hip_bfloat16* vptb  = (__hip_bfloat16*)(ws + 104202240);  // 12976128
  __hip_bfloat16* big   = (__hip_bfloat16*)(ws + 117178368);  // 154140672 (fc1 m1; earlier Q|KV|hp)
  const size_t WS_NEEDED = 117178368ull + 154140672ull;       // ~271.3 MB
  if (ws_size < WS_NEEDED) return;

  // sub-buffers carved from big (all consumed before fc1 overwrites big)
  __hip_bfloat16* qb   = big;                                        // 25088*768*2 = 38535168
  __hip_bfloat16* kvb  = (__hip_bfloat16*)((char*)big + 38535168);   // 8448*1536*2 = 25952256
  __hip_bfloat16* hp   = (__hip_bfloat16*)((char*)big + 64487424);   // 8448*768*2  = 12976128

  // weights -> bf16 (single vectorized launch)
  {
    int q0 = (2304 * 768) / 4, q1 = (768 * 768) / 4, q2 = (3072 * 768) / 4, q3 = (768 * 3072) / 4;
    int tot = q0 + q1 + q2 + q3;
    cvt_kernel<<<(tot + 255) / 256, 256, 0, stream>>>(qkv_w, wqkv, q0, proj_w, wproj, q1,
                                                      fc1_w, wfc1, q2, fc2_w, wfc2, q3);
  }

  // attention sublayer: pool-then-project for K/V (exact: pooling commutes with matmul)
  ln_kernel<<<M_, 256, 0, stream>>>(x, ln1_g, ln1_b, hbuf);
  gemm128b<<<(M_ / 128) * (768 / 128), 256, 0, stream>>>(hbuf, wqkv, qb, M_, 768, 768);
  pool_h_kernel<<<(B_ * NPP_ * C_) / 256, 256, 0, stream>>>(hbuf, hp);
  gemm128b<<<(MKV_ / 128) * (1536 / 128), 256, 0, stream>>>(hp, wqkv + 768 * 768, kvb, MKV_, 1536, 768);
  rearr_kernel<<<dim3(NPP_ / 32, B_ * H_), 256, 0, stream>>>(kvb, kpb, vptb);
  attn_kernel<<<dim3((N_ + 127) / 128, B_ * H_), 256, 0, stream>>>(qb, kpb, vptb, obuf);
  gemm128<<<(M_ / 128) * (768 / 128), 256, 0, stream>>>(obuf, wproj, proj_b, x, out, M_, 768, 768);

  // MLP sublayer (x1 lives in d_out)
  ln_kernel<<<M_, 256, 0, stream>>>(out, ln2_g, ln2_b, hbuf);
  gemm128g<<<(M_ / 128) * (3072 / 128), 256, 0, stream>>>(hbuf, wfc1, fc1_b, big, M_, 3072, 768);
  gemm128<<<(M_ / 128) * (768 / 128), 256, 0, stream>>>(big, wfc2, fc2_b, out, out, M_, 768, 3072);
}